// Round 14
// baseline (70.288 us; speedup 1.0000x reference)
//
#include <hip/hip_runtime.h>
#include <hip/hip_bf16.h>
#include <float.h>
#include <limits.h>

#define FEAT       256
#define GAMMA_F    0.1f
#define EPS_F      1e-8f
#define KSEL       64        // BUDGET
#define NBUCK      4096      // 12-bit histogram of flipped-float keys
#define KSHIFT     20        // key >> KSHIFT -> bucket
#define NB1        1024      // persistent score blocks (4096 waves = full occupancy)
#define NB3        64        // hist/select blocks
#define CPW        4         // candidates per wave
#define BCAP       64        // per-block survivor region (expected ~2 used)
#define CAP        4096      // final assembly capacity (= NB3 * BCAP)
#define ZWORDS     (NBUCK + NB3 + 3)   // ghist + counts + done + oflow + oflowCnt

// Monotonic float -> uint transform (ascending order preserved).
__device__ __forceinline__ unsigned key_of(float v) {
    unsigned u = __float_as_uint(v);
    return u ^ ((u >> 31) ? 0xFFFFFFFFu : 0x80000000u);
}

__device__ __forceinline__ bool comes_first(float va, int ia, float vb, int ib) {
    return (va > vb) || (va == vb && ia < ib);
}

// ---------------------------------------------------------------------------
// Kernel 1: edge scores -- EXACT R6/R13 kernel (46.2/46.4us anchor).
// DIAGNOSTIC THIS ROUND: launched 3x (once in pipeline position, twice after
// select). The extra launches are idempotent (same scores rewritten; ws
// re-zeroed after select has consumed it -- harmless). The dur_us delta vs
// the 46.4 anchor = 2 x K1_warm, disambiguating whether K1 (~30us?) or
// selection+overhead (~25us?) owns the budget.
// ---------------------------------------------------------------------------
__global__ __launch_bounds__(256) void edge_score_kernel(
    const float* __restrict__ infl,
    const float* __restrict__ feats,
    const int*   __restrict__ cand,
    const float* __restrict__ inj,
    float*       __restrict__ scores,   // d_out + KSEL
    unsigned*    __restrict__ ws_zero,  // ZWORDS words to clear
    int num_cand)
{
    const int gtid = blockIdx.x * blockDim.x + threadIdx.x;
    if (gtid < ZWORDS) ws_zero[gtid] = 0u;   // fire-and-forget

    const int lane    = threadIdx.x & 63;
    const int wid     = gtid >> 6;              // global wave id
    const int nwaves  = NB1 * 4;
    const int ngroups = (num_cand + CPW - 1) / CPW;

    const float4 g = *reinterpret_cast<const float4*>(inj + lane * 4);
    float ng = g.x * g.x + g.y * g.y + g.z * g.z + g.w * g.w;
    #pragma unroll
    for (int off = 32; off > 0; off >>= 1) ng += __shfl_xor(ng, off);
    const float inj_n = fmaxf(sqrtf(ng), EPS_F);

    for (int grp = wid; grp < ngroups; grp += nwaves) {
        const int base   = grp * CPW;
        const int n_here = num_cand - base;   // >= 1

        const int r0 = cand[base];
        const int r1 = (n_here > 1) ? cand[base + 1] : r0;
        const int r2 = (n_here > 2) ? cand[base + 2] : r0;
        const int r3 = (n_here > 3) ? cand[base + 3] : r0;
        const float4 f0 = *reinterpret_cast<const float4*>(feats + (size_t)r0 * FEAT + lane * 4);
        const float4 f1 = *reinterpret_cast<const float4*>(feats + (size_t)r1 * FEAT + lane * 4);
        const float4 f2 = *reinterpret_cast<const float4*>(feats + (size_t)r2 * FEAT + lane * 4);
        const float4 f3 = *reinterpret_cast<const float4*>(feats + (size_t)r3 * FEAT + lane * 4);

        float dot0 = f0.x*g.x + f0.y*g.y + f0.z*g.z + f0.w*g.w;
        float nf0  = f0.x*f0.x + f0.y*f0.y + f0.z*f0.z + f0.w*f0.w;
        float dot1 = f1.x*g.x + f1.y*g.y + f1.z*g.z + f1.w*g.w;
        float nf1  = f1.x*f1.x + f1.y*f1.y + f1.z*f1.z + f1.w*f1.w;
        float dot2 = f2.x*g.x + f2.y*g.y + f2.z*g.z + f2.w*g.w;
        float nf2  = f2.x*f2.x + f2.y*f2.y + f2.z*f2.z + f2.w*f2.w;
        float dot3 = f3.x*g.x + f3.y*g.y + f3.z*g.z + f3.w*g.w;
        float nf3  = f3.x*f3.x + f3.y*f3.y + f3.z*f3.z + f3.w*f3.w;

        #pragma unroll
        for (int off = 32; off > 0; off >>= 1) {
            dot0 += __shfl_xor(dot0, off);  nf0 += __shfl_xor(nf0, off);
            dot1 += __shfl_xor(dot1, off);  nf1 += __shfl_xor(nf1, off);
            dot2 += __shfl_xor(dot2, off);  nf2 += __shfl_xor(nf2, off);
            dot3 += __shfl_xor(dot3, off);  nf3 += __shfl_xor(nf3, off);
        }

        if (lane == 0) {
            const float s0 = infl[base] - GAMMA_F * (dot0 / (fmaxf(sqrtf(nf0), EPS_F) * inj_n));
            if (n_here >= 4) {
                const float s1 = infl[base+1] - GAMMA_F * (dot1 / (fmaxf(sqrtf(nf1), EPS_F) * inj_n));
                const float s2 = infl[base+2] - GAMMA_F * (dot2 / (fmaxf(sqrtf(nf2), EPS_F) * inj_n));
                const float s3 = infl[base+3] - GAMMA_F * (dot3 / (fmaxf(sqrtf(nf3), EPS_F) * inj_n));
                *reinterpret_cast<float4*>(scores + base) = make_float4(s0, s1, s2, s3);
            } else {
                scores[base] = s0;
                if (n_here > 1)
                    scores[base+1] = infl[base+1] - GAMMA_F * (dot1 / (fmaxf(sqrtf(nf1), EPS_F) * inj_n));
                if (n_here > 2)
                    scores[base+2] = infl[base+2] - GAMMA_F * (dot2 / (fmaxf(sqrtf(nf2), EPS_F) * inj_n));
            }
        }
    }
}

// ---------------------------------------------------------------------------
// Kernel 2: 12-bit histogram (unchanged R13).
// ---------------------------------------------------------------------------
__global__ __launch_bounds__(256) void hist_kernel(
    const float* __restrict__ scores,
    unsigned*    __restrict__ hist,
    int n)
{
    __shared__ unsigned h[NBUCK];
    for (int i = threadIdx.x; i < NBUCK; i += 256) h[i] = 0;
    __syncthreads();

    const int n4 = n >> 2;
    const float4* s4 = reinterpret_cast<const float4*>(scores);
    for (int g = blockIdx.x * 256 + threadIdx.x; g < n4; g += NB3 * 256) {
        const float4 v = s4[g];
        atomicAdd(&h[key_of(v.x) >> KSHIFT], 1u);
        atomicAdd(&h[key_of(v.y) >> KSHIFT], 1u);
        atomicAdd(&h[key_of(v.z) >> KSHIFT], 1u);
        atomicAdd(&h[key_of(v.w) >> KSHIFT], 1u);
    }
    if (blockIdx.x == 0 && threadIdx.x < (n & 3))
        atomicAdd(&h[key_of(scores[n4 * 4 + threadIdx.x]) >> KSHIFT], 1u);
    __syncthreads();

    for (int i = threadIdx.x; i < NBUCK; i += 256)
        if (h[i]) atomicAdd(&hist[i], h[i]);
}

// ---------------------------------------------------------------------------
// Kernel 3: select (unchanged R13).
// ---------------------------------------------------------------------------
__global__ __launch_bounds__(256) void select_kernel(
    const float*    __restrict__ scores,
    const unsigned* __restrict__ hist,
    unsigned*       __restrict__ counts,    // [NB3]
    unsigned*       __restrict__ done,
    unsigned*       __restrict__ oflow,     // flag + spill counter (2 words)
    float*          __restrict__ ws_v,      // [NB3*BCAP]
    int*            __restrict__ ws_i,      // [NB3*BCAP]
    const int*      __restrict__ cand,
    float*          __restrict__ out,       // d_out[0..KSEL)
    int n)
{
    __shared__ unsigned csum[256];
    __shared__ unsigned sB, sCnt;
    __shared__ int      sLast;
    __shared__ unsigned soff[NB3 + 1];
    __shared__ float    sv[CAP];
    __shared__ int      si[CAP];

    const int t   = threadIdx.x;
    const int bid = blockIdx.x;

    {
        const int hi = NBUCK - 16 * t;     // chunk t = buckets [hi-16, hi)
        unsigned s = 0;
        for (int b = hi - 16; b < hi; ++b) s += hist[b];
        csum[t] = s;
    }
    __syncthreads();
    if (t == 0) {
        unsigned cum = 0;
        int tc = 0;
        for (; tc < 256; ++tc) {
            if (cum + csum[tc] >= KSEL) break;
            cum += csum[tc];
        }
        unsigned B = 0;
        if (tc < 256) {
            int b = NBUCK - 16 * tc - 1;
            for (int k = 0; k < 16; ++k, --b) {
                cum += hist[b];
                if (cum >= KSEL) { B = (unsigned)b; break; }
            }
        }
        sB = B;
        sCnt = 0;
    }
    __syncthreads();
    const unsigned B = sB;

    const int n4 = n >> 2;
    const float4* s4 = reinterpret_cast<const float4*>(scores);
    for (int g = bid * 256 + t; g < n4; g += NB3 * 256) {
        const float4 v = s4[g];
        const float vv[4] = {v.x, v.y, v.z, v.w};
        #pragma unroll
        for (int j = 0; j < 4; ++j) {
            if ((key_of(vv[j]) >> KSHIFT) >= B) {
                const unsigned p = atomicAdd(&sCnt, 1u);   // LDS atomic
                if (p < BCAP) { ws_v[bid * BCAP + p] = vv[j]; ws_i[bid * BCAP + p] = g * 4 + j; }
            }
        }
    }
    if (bid == 0 && t < (n & 3)) {
        const float v = scores[n4 * 4 + t];
        if ((key_of(v) >> KSHIFT) >= B) {
            const unsigned p = atomicAdd(&sCnt, 1u);
            if (p < BCAP) { ws_v[p] = v; ws_i[p] = n4 * 4 + t; }
        }
    }
    __syncthreads();
    if (t == 0) {
        counts[bid] = min(sCnt, (unsigned)BCAP);
        if (sCnt > BCAP) atomicAdd(&oflow[0], 1u);   // never expected
    }

    __threadfence();
    __syncthreads();
    if (t == 0) sLast = (atomicAdd(done, 1u) == (unsigned)(NB3 - 1));
    __syncthreads();
    if (!sLast) return;
    __threadfence();

    int m;
    if (oflow[0] == 0u) {
        if (t == 0) {
            unsigned acc = 0;
            #pragma unroll
            for (int r = 0; r < NB3; ++r) { soff[r] = acc; acc += counts[r]; }
            soff[NB3] = acc;
        }
        __syncthreads();
        m = (int)soff[NB3];
        for (int idx = t; idx < NB3 * BCAP; idx += 256) {
            const int r = idx >> 6, j = idx & (BCAP - 1);
            if ((unsigned)j < counts[r]) {
                const unsigned dst = soff[r] + j;
                sv[dst] = ws_v[r * BCAP + j];
                si[dst] = ws_i[r * BCAP + j];
            }
        }
    } else {
        if (t == 0) sCnt = 0;
        __syncthreads();
        for (int g = t; g < n; g += 256) {
            const float v = scores[g];
            if ((key_of(v) >> KSHIFT) >= B) {
                const unsigned p = atomicAdd(&sCnt, 1u);
                if (p < CAP) { sv[p] = v; si[p] = g; }
            }
        }
        __syncthreads();
        m = (int)min(sCnt, (unsigned)CAP);
    }
    __syncthreads();

    if (m <= 256) {
        if (t >= m) { sv[t] = -INFINITY; si[t] = INT_MAX; }
        __syncthreads();
        for (int k = 2; k <= 256; k <<= 1) {
            for (int j = k >> 1; j > 0; j >>= 1) {
                const int p = t ^ j;
                if (p > t) {
                    const float va = sv[t], vb = sv[p];
                    const int   ia = si[t], ib = si[p];
                    const bool asc = ((t & k) == 0);
                    const bool doSwap = asc ? comes_first(vb, ib, va, ia)
                                            : comes_first(va, ia, vb, ib);
                    if (doSwap) { sv[t] = vb; si[t] = ib; sv[p] = va; si[p] = ia; }
                }
                __syncthreads();
            }
        }
        if (t < KSEL) out[t] = (float)cand[si[t]];
        return;
    }

    __shared__ float wv[4];
    __shared__ int   wbi[4], wbs[4];
    for (int i = t + m; i < CAP; i += 256) { sv[i] = -INFINITY; si[i] = INT_MAX; }
    __syncthreads();
    for (int k = 0; k < KSEL; ++k) {
        float bv = -INFINITY; int bi = INT_MAX; int bs = 0;
        for (int i = t; i < CAP; i += 256) {
            if (comes_first(sv[i], si[i], bv, bi)) { bv = sv[i]; bi = si[i]; bs = i; }
        }
        #pragma unroll
        for (int off = 32; off > 0; off >>= 1) {
            const float ov = __shfl_xor(bv, off);
            const int   oi = __shfl_xor(bi, off);
            const int   os = __shfl_xor(bs, off);
            if (comes_first(ov, oi, bv, bi)) { bv = ov; bi = oi; bs = os; }
        }
        const int w = t >> 6;
        if ((t & 63) == 0) { wv[w] = bv; wbi[w] = bi; wbs[w] = bs; }
        __syncthreads();
        if (t == 0) {
            float fv = wv[0]; int fi = wbi[0]; int fs = wbs[0];
            #pragma unroll
            for (int j = 1; j < 4; ++j)
                if (comes_first(wv[j], wbi[j], fv, fi)) { fv = wv[j]; fi = wbi[j]; fs = wbs[j]; }
            out[k] = (float)cand[fi];
            sv[fs] = -INFINITY;
            si[fs] = INT_MAX;
        }
        __syncthreads();
    }
}

extern "C" void kernel_launch(void* const* d_in, const int* in_sizes, int n_in,
                              void* d_out, int out_size, void* d_ws, size_t ws_size,
                              hipStream_t stream) {
    const float* infl  = (const float*)d_in[0];   // [num_cand]
    const float* feats = (const float*)d_in[1];   // [num_nodes, 256]
    const int*   cand  = (const int*)d_in[2];     // [num_cand]
    const float* inj   = (const float*)d_in[3];   // [256]

    const int num_cand = in_sizes[0];

    float* out    = (float*)d_out;          // [0..64): indices-as-f32
    float* scores = (float*)d_out + KSEL;   // [64..64+num_cand): edge scores

    unsigned* ws_hist   = (unsigned*)d_ws;            // NBUCK
    unsigned* ws_counts = ws_hist + NBUCK;            // NB3
    unsigned* ws_done   = ws_counts + NB3;            // 1
    unsigned* ws_oflow  = ws_done + 1;                // 2
    float*    ws_v      = (float*)(ws_oflow + 2);     // NB3*BCAP
    int*      ws_i      = (int*)(ws_v + NB3 * BCAP);  // NB3*BCAP

    // 1. Edge scores (persistent grid) + workspace zeroing.
    edge_score_kernel<<<NB1, 256, 0, stream>>>(
        infl, feats, cand, inj, scores, ws_hist, num_cand);

    // 2. Histogram (LDS pre-aggregated).
    hist_kernel<<<NB3, 256, 0, stream>>>(scores, ws_hist, num_cand);

    // 3. Threshold + contention-free compact + final top-64.
    select_kernel<<<NB3, 256, 0, stream>>>(
        scores, ws_hist, ws_counts, ws_done, ws_oflow, ws_v, ws_i, cand, out, num_cand);

    // 4+5. DIAGNOSTIC: two idempotent K1 re-runs (L3-warm). dur_us delta vs
    // the 46.4us anchor = 2 x K1_warm. They rewrite identical scores and
    // re-zero ws (already consumed); output is unchanged; deterministic.
    edge_score_kernel<<<NB1, 256, 0, stream>>>(
        infl, feats, cand, inj, scores, ws_hist, num_cand);
    edge_score_kernel<<<NB1, 256, 0, stream>>>(
        infl, feats, cand, inj, scores, ws_hist, num_cand);
}